// Round 1
// baseline (702.657 us; speedup 1.0000x reference)
//
#include <hip/hip_runtime.h>
#include <math.h>

#define BB 8192
#define FF 32
#define PP 512
#define HH 256
#define S  8   // samples per block

// W1T layout: [P/4][H][4] so thread j reads 4 consecutive-p weights as float4,
// coalesced across threads (1 KB per wave instruction).
__global__ void transpose_w1(const float* __restrict__ W1, float* __restrict__ W1T) {
    int p = blockIdx.x;     // 0..511
    int j = threadIdx.x;    // 0..255
    W1T[((p >> 2) * HH + j) * 4 + (p & 3)] = W1[j * PP + p];
}

__global__ __launch_bounds__(256, 4)
void fused_physchem(const float* __restrict__ phys,
                    const float* __restrict__ ratios,
                    const int*   __restrict__ lengths,
                    const float* __restrict__ gamma,
                    const float* __restrict__ beta,
                    const float* __restrict__ W1T,
                    const float* __restrict__ b1,
                    const float* __restrict__ W2,
                    const float* __restrict__ b2,
                    float* __restrict__ out) {
    constexpr int PADP = PP + 4;  // 516 floats: row stride 2064 B, multiple of 16 B
    __shared__ float wts[S][FF];
    __shared__ int   slen[S];
    __shared__ __align__(16) float xn[S][PADP];
    __shared__ float red[4][S][2];
    __shared__ float redy[4][S];

    const int tid  = threadIdx.x;
    const int wave = tid >> 6;
    const int lane = tid & 63;
    const int b0   = blockIdx.x * S;

    // ---- Phase 0: masked, normalized mixing weights (one 32-lane group per sample)
    {
        int s = tid >> 5;          // 0..7
        int f = tid & 31;          // 0..31
        int len = lengths[b0 + s];
        float r = ratios[(b0 + s) * FF + f];
        float w = (f < len) ? r : 0.0f;
        float sum = w;
        #pragma unroll
        for (int m = 16; m >= 1; m >>= 1) sum += __shfl_xor(sum, m, 32);
        wts[s][f] = w / (sum + 1e-8f);
        if (f == 0) slen[s] = len;
    }
    __syncthreads();

    // ---- Phase 1: ragged weighted mix. Thread owns p = {2*tid, 2*tid+1}.
    float2 acc[S];
    {
        const float2* phys2 = (const float2*)phys;
        #pragma unroll
        for (int s = 0; s < S; ++s) {
            float ax = 0.f, ay = 0.f;
            const int len = slen[s];
            const float2* row = phys2 + (size_t)(b0 + s) * FF * (PP / 2) + tid;
            #pragma unroll 4
            for (int f = 0; f < len; ++f) {
                float w  = wts[s][f];
                float2 v = row[(size_t)f * (PP / 2)];
                ax += w * v.x;
                ay += w * v.y;
            }
            acc[s].x = ax; acc[s].y = ay;
        }
    }

    // ---- Phase 2: LayerNorm (mean/var block-reduction per sample)
    float2 gb = ((const float2*)gamma)[tid];
    float2 bb = ((const float2*)beta)[tid];
    #pragma unroll
    for (int s = 0; s < S; ++s) {
        float sum = acc[s].x + acc[s].y;
        float sq  = acc[s].x * acc[s].x + acc[s].y * acc[s].y;
        #pragma unroll
        for (int m = 32; m >= 1; m >>= 1) {
            sum += __shfl_xor(sum, m, 64);
            sq  += __shfl_xor(sq,  m, 64);
        }
        if (lane == 0) { red[wave][s][0] = sum; red[wave][s][1] = sq; }
    }
    __syncthreads();
    #pragma unroll
    for (int s = 0; s < S; ++s) {
        float sum = red[0][s][0] + red[1][s][0] + red[2][s][0] + red[3][s][0];
        float sq  = red[0][s][1] + red[1][s][1] + red[2][s][1] + red[3][s][1];
        float mu  = sum * (1.0f / PP);
        float var = sq * (1.0f / PP) - mu * mu;
        float inv = rsqrtf(var + 1e-5f);
        xn[s][2 * tid]     = (acc[s].x - mu) * inv * gb.x + bb.x;
        xn[s][2 * tid + 1] = (acc[s].y - mu) * inv * gb.y + bb.y;
    }
    __syncthreads();

    // ---- Phase 3: MLP. Thread j computes h[j] for all S samples.
    float hacc[S];
    #pragma unroll
    for (int s = 0; s < S; ++s) hacc[s] = 0.f;
    {
        const int j = tid;
        for (int p0 = 0; p0 < PP; p0 += 4) {
            float4 wv = *(const float4*)&W1T[((p0 >> 2) * HH + j) * 4];
            #pragma unroll
            for (int s = 0; s < S; ++s) {
                float4 xv = *(const float4*)&xn[s][p0];   // LDS broadcast b128
                hacc[s] += wv.x * xv.x + wv.y * xv.y + wv.z * xv.z + wv.w * xv.w;
            }
        }
    }
    float b1j = b1[tid];
    float w2j = W2[tid];
    #pragma unroll
    for (int s = 0; s < S; ++s) {
        float h = hacc[s] + b1j;
        h = h > 0.f ? h : 0.f;
        float v = h * w2j;
        #pragma unroll
        for (int m = 32; m >= 1; m >>= 1) v += __shfl_xor(v, m, 64);
        if (lane == 0) redy[wave][s] = v;
    }
    __syncthreads();
    if (tid < S) {
        int s = tid;
        float y = redy[0][s] + redy[1][s] + redy[2][s] + redy[3][s] + b2[0];
        // nan_to_num semantics: nan->0, +inf->FLT_MAX, -inf->-FLT_MAX
        if (isnan(y)) y = 0.f;
        else if (isinf(y)) y = (y > 0.f) ? 3.402823466e38f : -3.402823466e38f;
        out[b0 + s] = y;
    }
}

extern "C" void kernel_launch(void* const* d_in, const int* in_sizes, int n_in,
                              void* d_out, int out_size, void* d_ws, size_t ws_size,
                              hipStream_t stream) {
    const float* phys    = (const float*)d_in[0];
    const float* ratios  = (const float*)d_in[1];
    const int*   lengths = (const int*)  d_in[2];
    const float* gamma   = (const float*)d_in[3];
    const float* beta    = (const float*)d_in[4];
    const float* W1      = (const float*)d_in[5];
    const float* b1      = (const float*)d_in[6];
    const float* W2      = (const float*)d_in[7];
    const float* b2      = (const float*)d_in[8];
    float* out = (float*)d_out;
    float* W1T = (float*)d_ws;   // needs 512*256*4 = 512 KiB of scratch

    transpose_w1<<<dim3(PP), dim3(HH), 0, stream>>>(W1, W1T);
    fused_physchem<<<dim3(BB / S), dim3(256), 0, stream>>>(
        phys, ratios, lengths, gamma, beta, W1T, b1, W2, b2, out);
}

// Round 2
// 700.370 us; speedup vs baseline: 1.0033x; 1.0033x over previous
//
#include <hip/hip_runtime.h>
#include <math.h>

#define BB 8192
#define FF 32
#define PP 512
#define HH 256
#define S  8   // samples per block

// W1T layout: [P/4][H][4] so thread j reads 4 consecutive-p weights as float4,
// coalesced across threads (1 KB per wave instruction).
__global__ void transpose_w1(const float* __restrict__ W1, float* __restrict__ W1T) {
    int p = blockIdx.x;     // 0..511
    int j = threadIdx.x;    // 0..255
    W1T[((p >> 2) * HH + j) * 4 + (p & 3)] = W1[j * PP + p];
}

__global__ __launch_bounds__(256, 4)
void fused_physchem(const float* __restrict__ phys,
                    const float* __restrict__ ratios,
                    const int*   __restrict__ lengths,
                    const float* __restrict__ gamma,
                    const float* __restrict__ beta,
                    const float* __restrict__ W1T,
                    const float* __restrict__ b1,
                    const float* __restrict__ W2,
                    const float* __restrict__ b2,
                    float* __restrict__ out) {
    constexpr int PADP = PP + 4;  // 516 floats: row stride 2064 B, 16 B aligned
    __shared__ float wts[S][FF];
    __shared__ int   slen[S];
    __shared__ __align__(16) float xn[S][PADP];
    __shared__ float red[4][4][2];   // [wave][pair k][sum,sq]
    __shared__ float redy[4][S];

    const int tid  = threadIdx.x;
    const int wave = tid >> 6;
    const int lane = tid & 63;
    const int b0   = blockIdx.x * S;

    // ---- Phase 0: masked, normalized mixing weights (one 32-lane group per sample)
    {
        int s = tid >> 5;          // 0..7
        int f = tid & 31;          // 0..31
        int len = lengths[b0 + s];
        float r = ratios[(b0 + s) * FF + f];
        float w = (f < len) ? r : 0.0f;
        float sum = w;
        #pragma unroll
        for (int m = 16; m >= 1; m >>= 1) sum += __shfl_xor(sum, m, 32);
        wts[s][f] = w / (sum + 1e-8f);
        if (f == 0) slen[s] = len;
    }
    __syncthreads();

    // ---- Phase 1: ragged weighted mix, float4 loads, 2 samples in flight.
    // Threads 0..127 (waves 0,1) handle sample 2k; threads 128..255 (waves 2,3)
    // handle sample 2k+1. Each thread owns float4 at p = 4*pt.
    const int pt = tid & 127;       // float4 index 0..127
    const int sh = tid >> 7;        // 0 or 1
    float4 mixacc[4];
    {
        const float4* phys4 = (const float4*)phys;
        #pragma unroll
        for (int k = 0; k < 4; ++k) {
            const int s   = 2 * k + sh;
            const int len = slen[s];
            const float4* row = phys4 + (size_t)(b0 + s) * FF * (PP / 4) + pt;
            float4 a = make_float4(0.f, 0.f, 0.f, 0.f);
            #pragma unroll 8
            for (int f = 0; f < len; ++f) {
                float  w = wts[s][f];
                float4 v = row[(size_t)f * (PP / 4)];
                a.x += w * v.x; a.y += w * v.y;
                a.z += w * v.z; a.w += w * v.w;
            }
            mixacc[k] = a;
        }
    }

    // ---- Phase 2: LayerNorm. Stats from registers (no LDS round-trip of mix).
    #pragma unroll
    for (int k = 0; k < 4; ++k) {
        float4 a = mixacc[k];
        float sum = a.x + a.y + a.z + a.w;
        float sq  = a.x * a.x + a.y * a.y + a.z * a.z + a.w * a.w;
        #pragma unroll
        for (int m = 32; m >= 1; m >>= 1) {
            sum += __shfl_xor(sum, m, 64);
            sq  += __shfl_xor(sq,  m, 64);
        }
        if (lane == 0) { red[wave][k][0] = sum; red[wave][k][1] = sq; }
    }
    __syncthreads();
    {
        float4 g  = ((const float4*)gamma)[pt];
        float4 be = ((const float4*)beta)[pt];
        const int wbase = sh * 2;   // waves {0,1} hold sample 2k; {2,3} hold 2k+1
        #pragma unroll
        for (int k = 0; k < 4; ++k) {
            const int s = 2 * k + sh;
            float sum = red[wbase][k][0] + red[wbase + 1][k][0];
            float sq  = red[wbase][k][1] + red[wbase + 1][k][1];
            float mu  = sum * (1.0f / PP);
            float var = sq * (1.0f / PP) - mu * mu;
            float inv = rsqrtf(var + 1e-5f);
            float4 a = mixacc[k];
            float4 o;
            o.x = (a.x - mu) * inv * g.x + be.x;
            o.y = (a.y - mu) * inv * g.y + be.y;
            o.z = (a.z - mu) * inv * g.z + be.z;
            o.w = (a.w - mu) * inv * g.w + be.w;
            *(float4*)&xn[s][4 * pt] = o;
        }
    }
    __syncthreads();

    // ---- Phase 3: MLP. Thread j computes h[j] for all S samples.
    float hacc[S];
    #pragma unroll
    for (int s = 0; s < S; ++s) hacc[s] = 0.f;
    {
        const int j = tid;
        for (int p0 = 0; p0 < PP; p0 += 4) {
            float4 wv = *(const float4*)&W1T[((p0 >> 2) * HH + j) * 4];
            #pragma unroll
            for (int s = 0; s < S; ++s) {
                float4 xv = *(const float4*)&xn[s][p0];   // LDS broadcast b128
                hacc[s] += wv.x * xv.x + wv.y * xv.y + wv.z * xv.z + wv.w * xv.w;
            }
        }
    }
    float b1j = b1[tid];
    float w2j = W2[tid];
    #pragma unroll
    for (int s = 0; s < S; ++s) {
        float h = hacc[s] + b1j;
        h = h > 0.f ? h : 0.f;
        float v = h * w2j;
        #pragma unroll
        for (int m = 32; m >= 1; m >>= 1) v += __shfl_xor(v, m, 64);
        if (lane == 0) redy[wave][s] = v;
    }
    __syncthreads();
    if (tid < S) {
        int s = tid;
        float y = redy[0][s] + redy[1][s] + redy[2][s] + redy[3][s] + b2[0];
        // nan_to_num semantics: nan->0, +inf->FLT_MAX, -inf->-FLT_MAX
        if (isnan(y)) y = 0.f;
        else if (isinf(y)) y = (y > 0.f) ? 3.402823466e38f : -3.402823466e38f;
        out[b0 + s] = y;
    }
}

extern "C" void kernel_launch(void* const* d_in, const int* in_sizes, int n_in,
                              void* d_out, int out_size, void* d_ws, size_t ws_size,
                              hipStream_t stream) {
    const float* phys    = (const float*)d_in[0];
    const float* ratios  = (const float*)d_in[1];
    const int*   lengths = (const int*)  d_in[2];
    const float* gamma   = (const float*)d_in[3];
    const float* beta    = (const float*)d_in[4];
    const float* W1      = (const float*)d_in[5];
    const float* b1      = (const float*)d_in[6];
    const float* W2      = (const float*)d_in[7];
    const float* b2      = (const float*)d_in[8];
    float* out = (float*)d_out;
    float* W1T = (float*)d_ws;   // needs 512*256*4 = 512 KiB of scratch

    transpose_w1<<<dim3(PP), dim3(HH), 0, stream>>>(W1, W1T);
    fused_physchem<<<dim3(BB / S), dim3(256), 0, stream>>>(
        phys, ratios, lengths, gamma, beta, W1T, b1, W2, b2, out);
}

// Round 3
// 688.633 us; speedup vs baseline: 1.0204x; 1.0170x over previous
//
#include <hip/hip_runtime.h>
#include <math.h>

#define BB 8192
#define FF 32
#define PP 512
#define HH 256
#define S  16   // samples per block; grid = 512

// W1T layout: [P/4][H][4] so in phase 3 lane j reads W1 for 4 consecutive p
// as one float4, coalesced across lanes (1 KB per wave instruction).
__global__ void transpose_w1(const float* __restrict__ W1, float* __restrict__ W1T) {
    int p = blockIdx.x;     // 0..511
    int j = threadIdx.x;    // 0..255
    W1T[((p >> 2) * HH + j) * 4 + (p & 3)] = W1[j * PP + p];
}

__global__ __launch_bounds__(256, 2)
void fused_physchem(const float* __restrict__ phys,
                    const float* __restrict__ ratios,
                    const int*   __restrict__ lengths,
                    const float* __restrict__ gamma,
                    const float* __restrict__ beta,
                    const float* __restrict__ W1T,
                    const float* __restrict__ b1,
                    const float* __restrict__ W2,
                    const float* __restrict__ b2,
                    float* __restrict__ out) {
    constexpr int PADP = PP + 4;  // 516 floats: row stride 2064 B, 16 B aligned
    __shared__ float wts[S][FF];
    __shared__ int   slen[S];
    __shared__ __align__(16) float xn[S][PADP];   // ~33 KB
    __shared__ float red[4][8][2];   // [wave][pair k][sum,sq]

    const int tid  = threadIdx.x;
    const int wave = tid >> 6;
    const int lane = tid & 63;
    const int b0   = blockIdx.x * S;

    // ---- Phase 0: masked, normalized mixing weights.
    // 8 groups of 32 lanes; group g handles samples g and g+8.
    {
        int g = tid >> 5;          // 0..7
        int f = tid & 31;          // 0..31
        #pragma unroll
        for (int rep = 0; rep < 2; ++rep) {
            int s = g + 8 * rep;
            int len = lengths[b0 + s];
            float r = ratios[(b0 + s) * FF + f];
            float w = (f < len) ? r : 0.0f;
            float sum = w;
            #pragma unroll
            for (int m = 16; m >= 1; m >>= 1) sum += __shfl_xor(sum, m, 32);
            wts[s][f] = w / (sum + 1e-8f);
            if (f == 0) slen[s] = len;
        }
    }
    __syncthreads();

    // ---- Phase 1: ragged weighted mix, float4 loads, 2 samples in flight.
    // Threads 0..127 (waves 0,1) handle even samples; 128..255 odd samples.
    const int pt = tid & 127;       // float4 index 0..127
    const int sh = tid >> 7;        // 0 or 1
    float4 mixacc[8];
    {
        const float4* phys4 = (const float4*)phys;
        #pragma unroll
        for (int k = 0; k < 8; ++k) {
            const int s   = 2 * k + sh;
            const int len = slen[s];
            const float4* row = phys4 + (size_t)(b0 + s) * FF * (PP / 4) + pt;
            float4 a = make_float4(0.f, 0.f, 0.f, 0.f);
            #pragma unroll 8
            for (int f = 0; f < len; ++f) {
                float  w = wts[s][f];
                float4 v = row[(size_t)f * (PP / 4)];
                a.x += w * v.x; a.y += w * v.y;
                a.z += w * v.z; a.w += w * v.w;
            }
            mixacc[k] = a;
        }
    }

    // ---- Phase 2: LayerNorm. Stats from registers.
    #pragma unroll
    for (int k = 0; k < 8; ++k) {
        float4 a = mixacc[k];
        float sum = a.x + a.y + a.z + a.w;
        float sq  = a.x * a.x + a.y * a.y + a.z * a.z + a.w * a.w;
        #pragma unroll
        for (int m = 32; m >= 1; m >>= 1) {
            sum += __shfl_xor(sum, m, 64);
            sq  += __shfl_xor(sq,  m, 64);
        }
        if (lane == 0) { red[wave][k][0] = sum; red[wave][k][1] = sq; }
    }
    __syncthreads();
    {
        float4 g  = ((const float4*)gamma)[pt];
        float4 be = ((const float4*)beta)[pt];
        const int wbase = sh * 2;   // waves {0,1}: even samples; {2,3}: odd
        #pragma unroll
        for (int k = 0; k < 8; ++k) {
            const int s = 2 * k + sh;
            float sum = red[wbase][k][0] + red[wbase + 1][k][0];
            float sq  = red[wbase][k][1] + red[wbase + 1][k][1];
            float mu  = sum * (1.0f / PP);
            float var = sq * (1.0f / PP) - mu * mu;
            float inv = rsqrtf(var + 1e-5f);
            float4 a = mixacc[k];
            float4 o;
            o.x = (a.x - mu) * inv * g.x + be.x;
            o.y = (a.y - mu) * inv * g.y + be.y;
            o.z = (a.z - mu) * inv * g.z + be.z;
            o.w = (a.w - mu) * inv * g.w + be.w;
            *(float4*)&xn[s][4 * pt] = o;
        }
    }
    __syncthreads();

    // ---- Phase 3: MLP. Wave w owns samples 4w..4w+3 and ALL 256 hidden units
    // (lane computes j = lane + 64*jj, jj=0..3). Per p-chunk: 4 coalesced W1T
    // float4 loads (L2) + 4 broadcast xn reads (LDS) + 64 FMAs -> LDS instr
    // count is 4x lower than j-per-thread, W1 L2 traffic 1.07 GB total.
    float hacc[4][4];
    #pragma unroll
    for (int t = 0; t < 4; ++t)
        #pragma unroll
        for (int jj = 0; jj < 4; ++jj) hacc[t][jj] = 0.f;
    {
        const int sb = wave * 4;
        const float4* W1T4 = (const float4*)W1T;
        for (int c = 0; c < PP / 4; ++c) {
            float4 wv[4];
            #pragma unroll
            for (int jj = 0; jj < 4; ++jj)
                wv[jj] = W1T4[c * HH + lane + 64 * jj];
            #pragma unroll
            for (int t = 0; t < 4; ++t) {
                float4 xv = *(const float4*)&xn[sb + t][4 * c];  // broadcast
                #pragma unroll
                for (int jj = 0; jj < 4; ++jj)
                    hacc[t][jj] += wv[jj].x * xv.x + wv[jj].y * xv.y
                                 + wv[jj].z * xv.z + wv[jj].w * xv.w;
            }
        }
    }
    // Epilogue: relu, W2, wave-local reduction (wave covers all j).
    {
        const int sb = wave * 4;
        float b1v[4], w2v[4];
        #pragma unroll
        for (int jj = 0; jj < 4; ++jj) {
            b1v[jj] = b1[lane + 64 * jj];
            w2v[jj] = W2[lane + 64 * jj];
        }
        float b2v = b2[0];
        #pragma unroll
        for (int t = 0; t < 4; ++t) {
            float v = 0.f;
            #pragma unroll
            for (int jj = 0; jj < 4; ++jj) {
                float h = hacc[t][jj] + b1v[jj];
                h = h > 0.f ? h : 0.f;
                v += h * w2v[jj];
            }
            #pragma unroll
            for (int m = 32; m >= 1; m >>= 1) v += __shfl_xor(v, m, 64);
            if (lane == 0) {
                float y = v + b2v;
                if (isnan(y)) y = 0.f;
                else if (isinf(y)) y = (y > 0.f) ? 3.402823466e38f : -3.402823466e38f;
                out[b0 + sb + t] = y;
            }
        }
    }
}

extern "C" void kernel_launch(void* const* d_in, const int* in_sizes, int n_in,
                              void* d_out, int out_size, void* d_ws, size_t ws_size,
                              hipStream_t stream) {
    const float* phys    = (const float*)d_in[0];
    const float* ratios  = (const float*)d_in[1];
    const int*   lengths = (const int*)  d_in[2];
    const float* gamma   = (const float*)d_in[3];
    const float* beta    = (const float*)d_in[4];
    const float* W1      = (const float*)d_in[5];
    const float* b1      = (const float*)d_in[6];
    const float* W2      = (const float*)d_in[7];
    const float* b2      = (const float*)d_in[8];
    float* out = (float*)d_out;
    float* W1T = (float*)d_ws;   // needs 512*256*4 = 512 KiB of scratch

    transpose_w1<<<dim3(PP), dim3(HH), 0, stream>>>(W1, W1T);
    fused_physchem<<<dim3(BB / S), dim3(256), 0, stream>>>(
        phys, ratios, lengths, gamma, beta, W1T, b1, W2, b2, out);
}